// Round 8
// baseline (185.689 us; speedup 1.0000x reference)
//
#include <hip/hip_runtime.h>
#include <hip/hip_bf16.h>

// ClusterLoss fused kernel for MI355X (gfx950).  R8.
// K-split for occupancy: each block holds HALF the centers (512x128 fp8 =
// 64 KB LDS, XOR-swizzled) + 16 KB swizzled A-tile = exactly 80 KB ->
// 2 blocks/CU co-resident (16 waves/CU, 4/SIMD) vs R7's 1 block (2/SIMD).
// Block pair (2m,2m+1) = same 512 rows x complementary center halves
// (adjacent dispatch -> shared L2 for the A stream). Per-row winners combine
// through global atomicMax on monotone-encoded keyed floats (low 10 bits =
// 1023-k, ties -> smaller k). Row norms -> global nf[N] (half 0 writes).
// finalize kernel decodes keys and reduces loss = 1 - 2 d na/nf + na^2.

#define D 128
#define NK 1024

typedef __attribute__((ext_vector_type(4))) float floatx4;

template <bool HI>
__device__ __forceinline__ unsigned int pk_fp8(float a, float b, unsigned int old) {
    return (unsigned int)__builtin_amdgcn_cvt_pk_fp8_f32(a, b, (int)old, HI);
}

__device__ __forceinline__ float key_pack(float v, unsigned int inv_k) {
    unsigned int u = __builtin_bit_cast(unsigned int, v);
    unsigned int r = (0x3FFu & inv_k) | (~0x3FFu & u);   // v_bfi_b32
    return __builtin_bit_cast(float, r);
}

// monotone float->uint map (no NaNs among real keys)
__device__ __forceinline__ unsigned int key_enc(float f) {
    unsigned int u = __builtin_bit_cast(unsigned int, f);
    return (u >> 31) ? ~u : (u | 0x80000000u);
}

// ---- Prep: normalize centers -> fp8; zero key[N] and d_out ----
__global__ void prep_centers(const float* __restrict__ centers,
                             unsigned char* __restrict__ chat,
                             float* __restrict__ cnorm,
                             unsigned int* __restrict__ key,
                             float* __restrict__ out) {
    const int k = blockIdx.x;            // 1024 blocks
    const int t = threadIdx.x;           // 128 threads
    float v = centers[(size_t)k * D + t];
    float s = v * v;
    #pragma unroll
    for (int m = 1; m <= 32; m <<= 1) s += __shfl_xor(s, m);
    __shared__ float ws2[2];
    if ((t & 63) == 0) ws2[t >> 6] = s;
    __syncthreads();
    float total = ws2[0] + ws2[1];
    float n = sqrtf(total);
    float neff = fmaxf(n, 1e-12f);
    float q = v / neff;
    chat[(size_t)k * D + t] = (unsigned char)(pk_fp8<false>(q, q, 0u) & 0xFFu);
    if (t == 0) cnorm[k] = n;
    key[k * 128 + t] = 0u;               // 1024*128 == N
    if (k == 0 && t == 0) out[0] = 0.0f;
}

// ---- Main: 512 blocks (pair p = bx>>1 rows, half = bx&1 centers) ----
__global__ __launch_bounds__(512, 2) void cluster_main(
    const float* __restrict__ feats,        // [N][128] fp32
    const unsigned char* __restrict__ chat, // [1024][128] fp8 e4m3
    unsigned int* __restrict__ key,         // [N] keyed-uint (atomicMax)
    float* __restrict__ nfg,                // [N] row sum-of-squares
    int rtPer) {

    extern __shared__ unsigned char lds[];
    unsigned char* Bs = lds;                 // 65536 B (512 centers, swizzled)
    unsigned char* As = lds + 512 * D;       // 16384 B (128 rows, swizzled)

    const int tid  = threadIdx.x;            // 0..511, 8 waves
    const int lane = tid & 63;
    const int wave = tid >> 6;
    const int wm   = wave & 1;               // row half (64 rows)
    const int wn   = wave >> 1;              // col slice (128 centers)
    const int m16  = lane & 15;
    const int quad = lane >> 4;              // 0..3
    const int q1   = quad >> 1, q0 = quad & 1;
    const int m8   = m16 & 7;

    const int half = blockIdx.x & 1;         // center half
    const int pair = blockIdx.x >> 1;        // row group

    // ---- Stage this half's B once: 4096 16B chunks, 8/thread ----
    {
        const unsigned char* bsrc = chat + (size_t)half * 512 * D;
        #pragma unroll
        for (int s = 0; s < 8; ++s) {
            int id = s * 512 + tid;
            int r  = id >> 3;                // local center row (0..511)
            int c  = id & 7;
            uint4 v = *(const uint4*)(bsrc + (size_t)r * D + c * 16);
            *(uint4*)&Bs[r * D + ((c ^ (r & 7)) << 4)] = v;
        }
    }

    for (int rt = 0; rt < rtPer; ++rt) {
        const int row0 = (pair * rtPer + rt) * 128;

        // ---- Stage A (coalesced float4 -> fp8, swizzled) + row sumsq ----
        #pragma unroll
        for (int s = 0; s < 8; ++s) {
            int id = s * 512 + tid;          // float4 chunk, 0..4095
            int r  = id >> 5;                // row (32 chunks/row)
            int c4 = id & 31;
            float4 v = *(const float4*)(feats + (size_t)(row0 + r) * D + c4 * 4);
            unsigned int w = pk_fp8<false>(v.x, v.y, 0u);
            w = pk_fp8<true>(v.z, v.w, w);
            int pc = (c4 >> 2) ^ (r & 7);
            *(unsigned int*)&As[r * D + pc * 16 + (c4 & 3) * 4] = w;
            float sq = v.x*v.x + v.y*v.y + v.z*v.z + v.w*v.w;
            #pragma unroll
            for (int m = 1; m <= 16; m <<= 1) sq += __shfl_xor(sq, m);
            if (half == 0 && (tid & 31) == 0) nfg[row0 + r] = sq;  // half 0 writes norms
        }
        __syncthreads();                     // A (and B on rt 0) visible

        // ---- A fragments from LDS ----
        long long afr[4][4];                 // [i][kk]
        #pragma unroll
        for (int i = 0; i < 4; ++i) {
            const int r = wm * 64 + i * 16 + m16;
            #pragma unroll
            for (int kk = 0; kk < 4; ++kk) {
                int pc = (2 * kk + q1) ^ m8;
                afr[i][kk] = *(const long long*)&As[r * D + pc * 16 + q0 * 8];
            }
        }

        float best[16];                      // keyed floats per (i,r) slot
        #pragma unroll
        for (int s = 0; s < 16; ++s) best[s] = -3.0e38f;

        // ---- barrier-free MFMA over this wave's 128-center slice ----
        #pragma unroll
        for (int ch = 0; ch < 4; ++ch) {     // 4 chunks of 32 centers
            const int clocal = wn * 128 + ch * 32;          // LDS-local center
            const int kglob  = half * 512 + clocal + m16;   // global center
            const unsigned int inv0 = 1023u - (unsigned)kglob;
            const unsigned int inv1 = inv0 - 16u;
            floatx4 acc[4][2];
            #pragma unroll
            for (int i = 0; i < 4; ++i)
                #pragma unroll
                for (int j = 0; j < 2; ++j)
                    acc[i][j] = (floatx4){0.f, 0.f, 0.f, 0.f};

            #pragma unroll
            for (int kk = 0; kk < 4; ++kk) {
                long long bfr[2];
                #pragma unroll
                for (int j = 0; j < 2; ++j) {
                    int r  = clocal + j * 16 + m16;
                    int pc = (2 * kk + q1) ^ m8;
                    bfr[j] = *(const long long*)&Bs[r * D + pc * 16 + q0 * 8];
                }
                #pragma unroll
                for (int i = 0; i < 4; ++i)
                    #pragma unroll
                    for (int j = 0; j < 2; ++j)
                        acc[i][j] = __builtin_amdgcn_mfma_f32_16x16x32_fp8_fp8(
                            afr[i][kk], bfr[j], acc[i][j], 0, 0, 0);
            }

            #pragma unroll
            for (int i = 0; i < 4; ++i)
                #pragma unroll
                for (int r = 0; r < 4; ++r) {
                    const int slot = i * 4 + r;
                    float c0 = key_pack(acc[i][0][r], inv0);
                    float c1 = key_pack(acc[i][1][r], inv1);
                    best[slot] = fmaxf(best[slot], fmaxf(c0, c1));
                }
        }

        // cross-m16 butterfly — pure max on keys
        #pragma unroll
        for (int mask = 1; mask <= 8; mask <<= 1)
            #pragma unroll
            for (int s = 0; s < 16; ++s)
                best[s] = fmaxf(best[s], __shfl_xor(best[s], mask));

        // per-row global combine: monotone-encoded atomicMax
        if (m16 == 0) {
            #pragma unroll
            for (int s = 0; s < 16; ++s) {
                int i = s >> 2, rr = s & 3;
                int row = wm * 64 + 16 * i + quad * 4 + rr;
                atomicMax(&key[row0 + row], key_enc(best[s]));
            }
        }
        __syncthreads();   // all waves done reading As before restage
    }
}

// ---- Finalize: decode keys, compute loss, reduce ----
__global__ __launch_bounds__(512, 1) void finalize(
    const unsigned int* __restrict__ key,
    const float* __restrict__ nfg,
    const float* __restrict__ cnorm,
    float* __restrict__ out, int N) {
    const int n = blockIdx.x * 512 + threadIdx.x;
    float lsum = 0.0f;
    if (n < N) {
        unsigned int ku = key[n];
        unsigned int u  = (ku >> 31) ? (ku & 0x7FFFFFFFu) : ~ku;
        int   ka = 1023 - (int)(u & 1023u);
        float d  = __builtin_bit_cast(float, (u & 0xFFFFFC00u) | 0x200u);
        float nf = fmaxf(sqrtf(nfg[n]), 1e-12f);
        float na = cnorm[ka];
        lsum = 1.0f - 2.0f * d * na / nf + na * na;
    }
    #pragma unroll
    for (int m = 1; m <= 32; m <<= 1) lsum += __shfl_xor(lsum, m);
    if ((threadIdx.x & 63) == 0) atomicAdd(out, lsum / (float)N);
}

extern "C" void kernel_launch(void* const* d_in, const int* in_sizes, int n_in,
                              void* d_out, int out_size, void* d_ws, size_t ws_size,
                              hipStream_t stream) {
    const float* feats   = (const float*)d_in[0];
    const float* centers = (const float*)d_in[1];
    const int N = in_sizes[0] / D;   // 131072
    const int K = in_sizes[1] / D;   // 1024

    char* ws = (char*)d_ws;
    unsigned char* chat  = (unsigned char*)ws;                 // 128 KB
    float*         cnorm = (float*)(ws + (size_t)K * D);       // 4 KB
    unsigned int*  keyb  = (unsigned int*)(ws + (size_t)K * D + K * sizeof(float));
    float*         nfg   = (float*)((char*)keyb + (size_t)N * sizeof(unsigned int));
    float* out = (float*)d_out;

    const int smem = 512 * D + 128 * D;   // 81920 B: exactly 2 blocks/CU
    (void)hipFuncSetAttribute((const void*)cluster_main,
                              hipFuncAttributeMaxDynamicSharedMemorySize, smem);

    prep_centers<<<K, D, 0, stream>>>(centers, chat, cnorm, keyb, out);

    const int pairs = 256;
    const int rtPer = N / (pairs * 128);     // 4
    cluster_main<<<2 * pairs, 512, smem, stream>>>(feats, chat, keyb, nfg, rtPer);

    finalize<<<(N + 511) / 512, 512, 0, stream>>>(keyb, nfg, cnorm, out, N);
}

// Round 9
// 158.692 us; speedup vs baseline: 1.1701x; 1.1701x over previous
//
#include <hip/hip_runtime.h>
#include <hip/hip_bf16.h>

// ClusterLoss fused kernel for MI355X (gfx950).  R9.
// Occupancy with SLACK: block = 512 thr, LDS = half-K centers (512 x 128 fp8
// = 64 KB) + BM=64 A-tile (8 KB) = 73.7 KB -> 2 blocks/CU (147 KB of 160)
// with 16 KB slack (R8's exact-fit 2x80 KB never co-scheduled). 16 waves/CU,
// 4/SIMD. Small per-wave state (rows 32 x cols 128) keeps VGPR ~90 under the
// launch_bounds(512,4) 128 budget -> no spill. A prefetched (4 float4/thread)
// under the MFMA phase. Keyed-float argmax (low 10 bits = 1023-k) combined
// via global atomicMax on monotone-encoded keys; finalize decodes + reduces
// loss = 1 - 2 d na/nf + na^2.

#define D 128
#define BM 64

typedef __attribute__((ext_vector_type(4))) float floatx4;

template <bool HI>
__device__ __forceinline__ unsigned int pk_fp8(float a, float b, unsigned int old) {
    return (unsigned int)__builtin_amdgcn_cvt_pk_fp8_f32(a, b, (int)old, HI);
}

__device__ __forceinline__ float key_pack(float v, unsigned int inv_k) {
    unsigned int u = __builtin_bit_cast(unsigned int, v);
    unsigned int r = (0x3FFu & inv_k) | (~0x3FFu & u);   // v_bfi_b32
    return __builtin_bit_cast(float, r);
}

__device__ __forceinline__ unsigned int key_enc(float f) {
    unsigned int u = __builtin_bit_cast(unsigned int, f);
    return (u >> 31) ? ~u : (u | 0x80000000u);
}

// ---- Prep: normalize centers -> fp8; zero key[N] and d_out ----
__global__ void prep_centers(const float* __restrict__ centers,
                             unsigned char* __restrict__ chat,
                             float* __restrict__ cnorm,
                             unsigned int* __restrict__ key,
                             float* __restrict__ out) {
    const int k = blockIdx.x;            // 1024 blocks
    const int t = threadIdx.x;           // 128 threads
    float v = centers[(size_t)k * D + t];
    float s = v * v;
    #pragma unroll
    for (int m = 1; m <= 32; m <<= 1) s += __shfl_xor(s, m);
    __shared__ float ws2[2];
    if ((t & 63) == 0) ws2[t >> 6] = s;
    __syncthreads();
    float total = ws2[0] + ws2[1];
    float n = sqrtf(total);
    float neff = fmaxf(n, 1e-12f);
    float q = v / neff;
    chat[(size_t)k * D + t] = (unsigned char)(pk_fp8<false>(q, q, 0u) & 0xFFu);
    if (t == 0) cnorm[k] = n;
    key[k * 128 + t] = 0u;               // 1024*128 == N
    if (k == 0 && t == 0) out[0] = 0.0f;
}

// ---- Main: 1024 blocks = 512 pairs x 2 center-halves; rtPer row-tiles ----
__global__ __launch_bounds__(512, 4) void cluster_main(
    const float* __restrict__ feats,        // [N][128] fp32
    const unsigned char* __restrict__ chat, // [1024][128] fp8 e4m3
    unsigned int* __restrict__ key,         // [N] keyed-uint (atomicMax)
    float* __restrict__ nfg,                // [N] row sum-of-squares
    int rtPer) {

    extern __shared__ unsigned char lds[];
    unsigned char* Bs = lds;                 // 65536 B (512 centers, swizzled)
    unsigned char* As = lds + 512 * D;       // 8192 B (64 rows, swizzled)

    const int tid  = threadIdx.x;            // 0..511, 8 waves
    const int lane = tid & 63;
    const int wave = tid >> 6;
    const int wm   = wave & 1;               // row half of the 64-row tile
    const int wn   = wave >> 1;              // 0..3: 128-center slice
    const int m16  = lane & 15;
    const int quad = lane >> 4;              // 0..3
    const int q1   = quad >> 1, q0 = quad & 1;
    const int m8   = m16 & 7;

    const int half = blockIdx.x & 1;         // center half (512 centers)
    const int pair = blockIdx.x >> 1;        // row group

    // ---- Stage this half's B once: 4096 16B chunks, 8/thread ----
    {
        const unsigned char* bsrc = chat + (size_t)half * 512 * D;
        #pragma unroll
        for (int s = 0; s < 8; ++s) {
            int id = s * 512 + tid;
            int r  = id >> 3;                // local center row (0..511)
            int c  = id & 7;
            uint4 v = *(const uint4*)(bsrc + (size_t)r * D + c * 16);
            *(uint4*)&Bs[r * D + ((c ^ (r & 7)) << 4)] = v;
        }
    }

    // ---- Prefetch A for rt=0: 4 float4/thread, coalesced ----
    float4 v[4];
    {
        const int row0 = pair * rtPer * BM;
        #pragma unroll
        for (int s = 0; s < 4; ++s) {
            int id = s * 512 + tid;          // 0..2047
            int r  = id >> 5;                // row (32 chunks/row)
            int c4 = id & 31;
            v[s] = *(const float4*)(feats + (size_t)(row0 + r) * D + c4 * 4);
        }
    }

    for (int rt = 0; rt < rtPer; ++rt) {
        const int row0 = (pair * rtPer + rt) * BM;

        // ---- Convert prefetched A -> fp8 swizzled LDS + row sumsq ----
        #pragma unroll
        for (int s = 0; s < 4; ++s) {
            int id = s * 512 + tid;
            int r  = id >> 5;
            int c4 = id & 31;
            float4 t = v[s];
            unsigned int w = pk_fp8<false>(t.x, t.y, 0u);
            w = pk_fp8<true>(t.z, t.w, w);
            int pc = (c4 >> 2) ^ (r & 7);
            *(unsigned int*)&As[r * D + pc * 16 + (c4 & 3) * 4] = w;
            float sq = t.x*t.x + t.y*t.y + t.z*t.z + t.w*t.w;
            #pragma unroll
            for (int m = 1; m <= 16; m <<= 1) sq += __shfl_xor(sq, m);
            if (half == 0 && (tid & 31) == 0) nfg[row0 + r] = sq;
        }
        __syncthreads();                     // As (and Bs on rt 0) visible

        // ---- Prefetch next A tile (rides under the MFMA phase) ----
        if (rt + 1 < rtPer) {
            const int nrow0 = row0 + BM;
            #pragma unroll
            for (int s = 0; s < 4; ++s) {
                int id = s * 512 + tid;
                int r  = id >> 5;
                int c4 = id & 31;
                v[s] = *(const float4*)(feats + (size_t)(nrow0 + r) * D + c4 * 4);
            }
        }

        // ---- A fragments from LDS ----
        long long afr[2][4];                 // [i][kk]
        #pragma unroll
        for (int i = 0; i < 2; ++i) {
            const int r = wm * 32 + i * 16 + m16;
            #pragma unroll
            for (int kk = 0; kk < 4; ++kk) {
                int pc = (2 * kk + q1) ^ m8;
                afr[i][kk] = *(const long long*)&As[r * D + pc * 16 + q0 * 8];
            }
        }

        float best[8];                       // keyed floats per (i,r) slot
        #pragma unroll
        for (int s = 0; s < 8; ++s) best[s] = -3.0e38f;

        // ---- barrier-free MFMA over this wave's 128-center slice ----
        #pragma unroll
        for (int ch = 0; ch < 4; ++ch) {     // 4 chunks of 32 centers
            const int clocal = wn * 128 + ch * 32;
            const int kglob  = half * 512 + clocal + m16;
            const unsigned int inv0 = 1023u - (unsigned)kglob;
            const unsigned int inv1 = inv0 - 16u;
            floatx4 acc[2][2];
            #pragma unroll
            for (int i = 0; i < 2; ++i)
                #pragma unroll
                for (int j = 0; j < 2; ++j)
                    acc[i][j] = (floatx4){0.f, 0.f, 0.f, 0.f};

            #pragma unroll
            for (int kk = 0; kk < 4; ++kk) {
                long long bfr[2];
                #pragma unroll
                for (int j = 0; j < 2; ++j) {
                    int rr = clocal + j * 16 + m16;
                    int pc = (2 * kk + q1) ^ m8;
                    bfr[j] = *(const long long*)&Bs[rr * D + pc * 16 + q0 * 8];
                }
                #pragma unroll
                for (int i = 0; i < 2; ++i)
                    #pragma unroll
                    for (int j = 0; j < 2; ++j)
                        acc[i][j] = __builtin_amdgcn_mfma_f32_16x16x32_fp8_fp8(
                            afr[i][kk], bfr[j], acc[i][j], 0, 0, 0);
            }

            #pragma unroll
            for (int i = 0; i < 2; ++i)
                #pragma unroll
                for (int r = 0; r < 4; ++r) {
                    const int slot = i * 4 + r;
                    float c0 = key_pack(acc[i][0][r], inv0);
                    float c1 = key_pack(acc[i][1][r], inv1);
                    best[slot] = fmaxf(best[slot], fmaxf(c0, c1));
                }
        }

        // cross-m16 butterfly — pure max on keys
        #pragma unroll
        for (int mask = 1; mask <= 8; mask <<= 1)
            #pragma unroll
            for (int s = 0; s < 8; ++s)
                best[s] = fmaxf(best[s], __shfl_xor(best[s], mask));

        // per-row global combine: monotone-encoded atomicMax
        if (m16 == 0) {
            #pragma unroll
            for (int s = 0; s < 8; ++s) {
                int i = s >> 2, rr = s & 3;
                int row = wm * 32 + i * 16 + quad * 4 + rr;
                atomicMax(&key[row0 + row], key_enc(best[s]));
            }
        }
        __syncthreads();   // all waves done reading As before restage
    }
}

// ---- Finalize: decode keys, compute loss, reduce ----
__global__ __launch_bounds__(512, 1) void finalize(
    const unsigned int* __restrict__ key,
    const float* __restrict__ nfg,
    const float* __restrict__ cnorm,
    float* __restrict__ out, int N) {
    const int n = blockIdx.x * 512 + threadIdx.x;
    float lsum = 0.0f;
    if (n < N) {
        unsigned int ku = key[n];
        unsigned int u  = (ku >> 31) ? (ku & 0x7FFFFFFFu) : ~ku;
        int   ka = 1023 - (int)(u & 1023u);
        float d  = __builtin_bit_cast(float, (u & 0xFFFFFC00u) | 0x200u);
        float nf = fmaxf(sqrtf(nfg[n]), 1e-12f);
        float na = cnorm[ka];
        lsum = 1.0f - 2.0f * d * na / nf + na * na;
    }
    #pragma unroll
    for (int m = 1; m <= 32; m <<= 1) lsum += __shfl_xor(lsum, m);
    if ((threadIdx.x & 63) == 0) atomicAdd(out, lsum / (float)N);
}

extern "C" void kernel_launch(void* const* d_in, const int* in_sizes, int n_in,
                              void* d_out, int out_size, void* d_ws, size_t ws_size,
                              hipStream_t stream) {
    const float* feats   = (const float*)d_in[0];
    const float* centers = (const float*)d_in[1];
    const int N = in_sizes[0] / D;   // 131072
    const int K = in_sizes[1] / D;   // 1024

    char* ws = (char*)d_ws;
    unsigned char* chat  = (unsigned char*)ws;                 // 128 KB
    float*         cnorm = (float*)(ws + (size_t)K * D);       // 4 KB
    unsigned int*  keyb  = (unsigned int*)(ws + (size_t)K * D + K * sizeof(float));
    float*         nfg   = (float*)((char*)keyb + (size_t)N * sizeof(unsigned int));
    float* out = (float*)d_out;

    const int smem = 512 * D + BM * D;   // 73728 B -> 2 blocks/CU with slack
    (void)hipFuncSetAttribute((const void*)cluster_main,
                              hipFuncAttributeMaxDynamicSharedMemorySize, smem);

    prep_centers<<<K, D, 0, stream>>>(centers, chat, cnorm, keyb, out);

    const int rtPer = 4;
    const int pairs = N / (rtPer * BM);      // 512
    cluster_main<<<2 * pairs, 512, smem, stream>>>(feats, chat, keyb, nfg, rtPer);

    finalize<<<(N + 511) / 512, 512, 0, stream>>>(keyb, nfg, cnorm, out, N);
}

// Round 10
// 150.473 us; speedup vs baseline: 1.2340x; 1.0546x over previous
//
#include <hip/hip_runtime.h>
#include <hip/hip_bf16.h>

// ClusterLoss fused kernel for MI355X (gfx950).  R10.
// = R9 structure (half-K fp8 centers in 64 KB LDS + BM=64 A-tile, 73.7 KB ->
// 2 blocks/CU, keyed-float argmax) with three fixes from R9 counters:
//  1) XCD-aware pairing: grid=512 all-co-resident, pair=bx&255, half=bx>>8.
//     Blocks p and p+256 share an XCD (256%8==0) -> A fetched once per pair
//     (R9: 66 MB double-fetch, pairs split across XCDs). rtPer=8, B staged
//     once per block (single dispatch round).
//  2) No global atomics: (half,row) winner is block-exclusive -> LDS combine
//     over wn then plain store to kbuf[half*N+row]; finalize fmaxes 2 halves.
//     (R9: ~1M cross-XCD atomicMax = 16.9 MB WRITE.)
//  3) half==1 skips the row-sumsq chain (wave-uniform).
// loss_n = 1 - 2 d na/nf + na^2 (fp32 scalars), keyed low-10-bits = 1023-k.

#define D 128
#define BM 64

typedef __attribute__((ext_vector_type(4))) float floatx4;

template <bool HI>
__device__ __forceinline__ unsigned int pk_fp8(float a, float b, unsigned int old) {
    return (unsigned int)__builtin_amdgcn_cvt_pk_fp8_f32(a, b, (int)old, HI);
}

__device__ __forceinline__ float key_pack(float v, unsigned int inv_k) {
    unsigned int u = __builtin_bit_cast(unsigned int, v);
    unsigned int r = (0x3FFu & inv_k) | (~0x3FFu & u);   // v_bfi_b32
    return __builtin_bit_cast(float, r);
}

// ---- Prep: normalize centers -> fp8; zero d_out ----
__global__ void prep_centers(const float* __restrict__ centers,
                             unsigned char* __restrict__ chat,
                             float* __restrict__ cnorm,
                             float* __restrict__ out) {
    const int k = blockIdx.x;            // 1024 blocks
    const int t = threadIdx.x;           // 128 threads
    float v = centers[(size_t)k * D + t];
    float s = v * v;
    #pragma unroll
    for (int m = 1; m <= 32; m <<= 1) s += __shfl_xor(s, m);
    __shared__ float ws2[2];
    if ((t & 63) == 0) ws2[t >> 6] = s;
    __syncthreads();
    float total = ws2[0] + ws2[1];
    float n = sqrtf(total);
    float neff = fmaxf(n, 1e-12f);
    float q = v / neff;
    chat[(size_t)k * D + t] = (unsigned char)(pk_fp8<false>(q, q, 0u) & 0xFFu);
    if (t == 0) cnorm[k] = n;
    if (k == 0 && t == 0) out[0] = 0.0f;
}

// ---- Main: 512 blocks = 256 pairs x 2 center-halves; 8 row-tiles each ----
__global__ __launch_bounds__(512, 4) void cluster_main(
    const float* __restrict__ feats,        // [N][128] fp32
    const unsigned char* __restrict__ chat, // [1024][128] fp8 e4m3
    float* __restrict__ kbuf,               // [2][N] keyed floats
    float* __restrict__ nfg,                // [N] row sum-of-squares
    int N, int rtPer) {

    extern __shared__ unsigned char lds[];
    unsigned char* Bs = lds;                 // 65536 B (512 centers, swizzled)
    unsigned char* As = lds + 512 * D;       // 8192 B (64 rows, swizzled)
    __shared__ float bv[4][BM];              // per-(wn,row) keyed floats

    const int tid  = threadIdx.x;            // 0..511, 8 waves
    const int lane = tid & 63;
    const int wave = tid >> 6;
    const int wm   = wave & 1;               // row half of the 64-row tile
    const int wn   = wave >> 1;              // 0..3: 128-center slice
    const int m16  = lane & 15;
    const int quad = lane >> 4;              // 0..3
    const int q1   = quad >> 1, q0 = quad & 1;
    const int m8   = m16 & 7;

    const int pair = blockIdx.x & 255;       // row group (0..255)
    const int half = blockIdx.x >> 8;        // center half; p and p+256 share an XCD

    // ---- Stage this half's B once: 4096 16B chunks, 8/thread ----
    {
        const unsigned char* bsrc = chat + (size_t)half * 512 * D;
        #pragma unroll
        for (int s = 0; s < 8; ++s) {
            int id = s * 512 + tid;
            int r  = id >> 3;                // local center row (0..511)
            int c  = id & 7;
            uint4 v = *(const uint4*)(bsrc + (size_t)r * D + c * 16);
            *(uint4*)&Bs[r * D + ((c ^ (r & 7)) << 4)] = v;
        }
    }

    // ---- Prefetch A for rt=0: 4 float4/thread, coalesced ----
    float4 v[4];
    {
        const int row0 = pair * rtPer * BM;
        #pragma unroll
        for (int s = 0; s < 4; ++s) {
            int id = s * 512 + tid;          // 0..2047
            int r  = id >> 5;                // row (32 chunks/row)
            int c4 = id & 31;
            v[s] = *(const float4*)(feats + (size_t)(row0 + r) * D + c4 * 4);
        }
    }

    for (int rt = 0; rt < rtPer; ++rt) {
        const int row0 = (pair * rtPer + rt) * BM;

        // ---- Convert prefetched A -> fp8 swizzled LDS (+ sumsq, half 0) ----
        #pragma unroll
        for (int s = 0; s < 4; ++s) {
            int id = s * 512 + tid;
            int r  = id >> 5;
            int c4 = id & 31;
            float4 t = v[s];
            unsigned int w = pk_fp8<false>(t.x, t.y, 0u);
            w = pk_fp8<true>(t.z, t.w, w);
            int pc = (c4 >> 2) ^ (r & 7);
            *(unsigned int*)&As[r * D + pc * 16 + (c4 & 3) * 4] = w;
            if (half == 0) {                 // wave-uniform: half 1 skips
                float sq = t.x*t.x + t.y*t.y + t.z*t.z + t.w*t.w;
                #pragma unroll
                for (int m = 1; m <= 16; m <<= 1) sq += __shfl_xor(sq, m);
                if ((tid & 31) == 0) nfg[row0 + r] = sq;
            }
        }
        __syncthreads();                     // As (and Bs on rt 0) visible

        // ---- Prefetch next A tile (rides under the MFMA phase) ----
        if (rt + 1 < rtPer) {
            const int nrow0 = row0 + BM;
            #pragma unroll
            for (int s = 0; s < 4; ++s) {
                int id = s * 512 + tid;
                int r  = id >> 5;
                int c4 = id & 31;
                v[s] = *(const float4*)(feats + (size_t)(nrow0 + r) * D + c4 * 4);
            }
        }

        // ---- A fragments from LDS ----
        long long afr[2][4];                 // [i][kk]
        #pragma unroll
        for (int i = 0; i < 2; ++i) {
            const int r = wm * 32 + i * 16 + m16;
            #pragma unroll
            for (int kk = 0; kk < 4; ++kk) {
                int pc = (2 * kk + q1) ^ m8;
                afr[i][kk] = *(const long long*)&As[r * D + pc * 16 + q0 * 8];
            }
        }

        float best[8];                       // keyed floats per (i,r) slot
        #pragma unroll
        for (int s = 0; s < 8; ++s) best[s] = -3.0e38f;

        // ---- barrier-free MFMA over this wave's 128-center slice ----
        #pragma unroll
        for (int ch = 0; ch < 4; ++ch) {     // 4 chunks of 32 centers
            const int clocal = wn * 128 + ch * 32;
            const int kglob  = half * 512 + clocal + m16;
            const unsigned int inv0 = 1023u - (unsigned)kglob;
            const unsigned int inv1 = inv0 - 16u;
            floatx4 acc[2][2];
            #pragma unroll
            for (int i = 0; i < 2; ++i)
                #pragma unroll
                for (int j = 0; j < 2; ++j)
                    acc[i][j] = (floatx4){0.f, 0.f, 0.f, 0.f};

            #pragma unroll
            for (int kk = 0; kk < 4; ++kk) {
                long long bfr[2];
                #pragma unroll
                for (int j = 0; j < 2; ++j) {
                    int rr = clocal + j * 16 + m16;
                    int pc = (2 * kk + q1) ^ m8;
                    bfr[j] = *(const long long*)&Bs[rr * D + pc * 16 + q0 * 8];
                }
                #pragma unroll
                for (int i = 0; i < 2; ++i)
                    #pragma unroll
                    for (int j = 0; j < 2; ++j)
                        acc[i][j] = __builtin_amdgcn_mfma_f32_16x16x32_fp8_fp8(
                            afr[i][kk], bfr[j], acc[i][j], 0, 0, 0);
            }

            #pragma unroll
            for (int i = 0; i < 2; ++i)
                #pragma unroll
                for (int r = 0; r < 4; ++r) {
                    const int slot = i * 4 + r;
                    float c0 = key_pack(acc[i][0][r], inv0);
                    float c1 = key_pack(acc[i][1][r], inv1);
                    best[slot] = fmaxf(best[slot], fmaxf(c0, c1));
                }
        }

        // cross-m16 butterfly — pure max on keys
        #pragma unroll
        for (int mask = 1; mask <= 8; mask <<= 1)
            #pragma unroll
            for (int s = 0; s < 8; ++s)
                best[s] = fmaxf(best[s], __shfl_xor(best[s], mask));

        // per-wave winners -> LDS
        if (m16 == 0) {
            #pragma unroll
            for (int s = 0; s < 8; ++s) {
                int i = s >> 2, rr = s & 3;
                int row = wm * 32 + i * 16 + quad * 4 + rr;
                bv[wn][row] = best[s];
            }
        }
        __syncthreads();                     // bv visible; As safe to restage

        // combine 4 wn-slices; plain store (block-exclusive per half,row)
        if (tid < BM) {
            float kmax = fmaxf(fmaxf(bv[0][tid], bv[1][tid]),
                               fmaxf(bv[2][tid], bv[3][tid]));
            kbuf[(size_t)half * N + row0 + tid] = kmax;
        }
        // next bv write happens only after the next rt's staging barrier,
        // so the combine-read above cannot race it.
    }
}

// ---- Finalize: fmax the two halves, decode, loss, reduce ----
__global__ __launch_bounds__(512, 1) void finalize(
    const float* __restrict__ kbuf,
    const float* __restrict__ nfg,
    const float* __restrict__ cnorm,
    float* __restrict__ out, int N) {
    const int n = blockIdx.x * 512 + threadIdx.x;
    float lsum = 0.0f;
    if (n < N) {
        float kmax = fmaxf(kbuf[n], kbuf[(size_t)N + n]);
        unsigned int u = __builtin_bit_cast(unsigned int, kmax);
        int   ka = 1023 - (int)(u & 1023u);
        float d  = __builtin_bit_cast(float, (u & 0xFFFFFC00u) | 0x200u);
        float nf = fmaxf(sqrtf(nfg[n]), 1e-12f);
        float na = cnorm[ka];
        lsum = 1.0f - 2.0f * d * na / nf + na * na;
    }
    #pragma unroll
    for (int m = 1; m <= 32; m <<= 1) lsum += __shfl_xor(lsum, m);
    if ((threadIdx.x & 63) == 0) atomicAdd(out, lsum / (float)N);
}

extern "C" void kernel_launch(void* const* d_in, const int* in_sizes, int n_in,
                              void* d_out, int out_size, void* d_ws, size_t ws_size,
                              hipStream_t stream) {
    const float* feats   = (const float*)d_in[0];
    const float* centers = (const float*)d_in[1];
    const int N = in_sizes[0] / D;   // 131072
    const int K = in_sizes[1] / D;   // 1024

    char* ws = (char*)d_ws;
    unsigned char* chat  = (unsigned char*)ws;                   // 128 KB
    float*         cnorm = (float*)(ws + (size_t)K * D);         // 4 KB
    float*         kbuf  = (float*)(ws + (size_t)K * D + K * sizeof(float)); // 2N floats = 1 MB
    float*         nfg   = (float*)((char*)kbuf + (size_t)2 * N * sizeof(float)); // N floats
    float* out = (float*)d_out;

    const int smem = 512 * D + BM * D;   // 73728 B -> 2 blocks/CU with slack
    (void)hipFuncSetAttribute((const void*)cluster_main,
                              hipFuncAttributeMaxDynamicSharedMemorySize, smem);

    prep_centers<<<K, D, 0, stream>>>(centers, chat, cnorm, out);

    const int rtPer = 8;
    const int pairs = N / (rtPer * BM);      // 256
    cluster_main<<<2 * pairs, 512, smem, stream>>>(feats, chat, kbuf, nfg, N, rtPer);

    finalize<<<(N + 511) / 512, 512, 0, stream>>>(kbuf, nfg, cnorm, out, N);
}